// Round 1
// baseline (319.828 us; speedup 1.0000x reference)
//
#include <hip/hip_runtime.h>

constexpr int IN_F  = 128;
constexpr int OUT_F = 64;

// h = feats @ weight  ([N,128] @ [128,64] -> [N,64])
__global__ void gemm_kernel(const float* __restrict__ feats,
                            const float* __restrict__ weight,
                            float* __restrict__ h, int total /* = N*64 */) {
    __shared__ float w[IN_F][OUT_F];  // 32 KB
    for (int i = threadIdx.x; i < IN_F * OUT_F; i += blockDim.x)
        w[i >> 6][i & 63] = weight[i];
    __syncthreads();

    const int stride = gridDim.x * blockDim.x;
    for (int idx = blockIdx.x * blockDim.x + threadIdx.x; idx < total; idx += stride) {
        const int n = idx >> 6;   // node
        const int j = idx & 63;   // output col
        const float4* frow = reinterpret_cast<const float4*>(feats + (size_t)n * IN_F);
        float acc = 0.f;
        #pragma unroll
        for (int k4 = 0; k4 < IN_F / 4; ++k4) {
            float4 f = frow[k4];   // wave-uniform broadcast (all 64 lanes same n)
            acc += f.x * w[k4 * 4 + 0][j];
            acc += f.y * w[k4 * 4 + 1][j];
            acc += f.z * w[k4 * 4 + 2][j];
            acc += f.w * w[k4 * 4 + 3][j];
        }
        h[idx] = acc;
    }
}

// One wave per edge: lane j does out[dst*64+j] += h[src*64+j]
__global__ void edge_kernel(const float* __restrict__ h,
                            const int* __restrict__ src,
                            const int* __restrict__ dst,
                            float* __restrict__ out, int n_edges) {
    const int lane        = threadIdx.x & 63;
    const int wave        = (blockIdx.x * blockDim.x + threadIdx.x) >> 6;
    const int total_waves = (gridDim.x * blockDim.x) >> 6;
    for (int e = wave; e < n_edges; e += total_waves) {
        const int s = src[e];  // same addr across wave -> broadcast load
        const int d = dst[e];
        const float v = h[(size_t)s * OUT_F + lane];
        atomicAdd(&out[(size_t)d * OUT_F + lane], v);
    }
}

// out = relu(out + bias), float4-vectorized
__global__ void bias_relu_kernel(float* __restrict__ out,
                                 const float* __restrict__ bias,
                                 int total4 /* = N*64/4 */) {
    const float4* b4 = reinterpret_cast<const float4*>(bias);
    float4* o4 = reinterpret_cast<float4*>(out);
    const int stride = gridDim.x * blockDim.x;
    for (int i = blockIdx.x * blockDim.x + threadIdx.x; i < total4; i += stride) {
        float4 v = o4[i];
        const float4 b = b4[i & 15];  // 64 cols = 16 float4s
        v.x = fmaxf(v.x + b.x, 0.f);
        v.y = fmaxf(v.y + b.y, 0.f);
        v.z = fmaxf(v.z + b.z, 0.f);
        v.w = fmaxf(v.w + b.w, 0.f);
        o4[i] = v;
    }
}

extern "C" void kernel_launch(void* const* d_in, const int* in_sizes, int n_in,
                              void* d_out, int out_size, void* d_ws, size_t ws_size,
                              hipStream_t stream) {
    const float* feats  = (const float*)d_in[0];
    const float* weight = (const float*)d_in[1];
    const float* bias   = (const float*)d_in[2];
    const int*   src    = (const int*)d_in[3];
    const int*   dst    = (const int*)d_in[4];
    float* out = (float*)d_out;
    float* h   = (float*)d_ws;  // N*64 floats = 12.8 MB scratch

    const int n_nodes = in_sizes[0] / IN_F;
    const int n_edges = in_sizes[3];
    const int total_h = n_nodes * OUT_F;

    // d_out is poisoned with 0xAA before every launch — zero it for the atomics.
    hipMemsetAsync(d_out, 0, (size_t)out_size * sizeof(float), stream);

    gemm_kernel<<<2048, 256, 0, stream>>>(feats, weight, h, total_h);
    // 2048 blocks x 256 threads = 8192 waves = full residency (256 CU x 32 waves)
    edge_kernel<<<2048, 256, 0, stream>>>(h, src, dst, out, n_edges);
    bias_relu_kernel<<<1024, 256, 0, stream>>>(out, bias, total_h / 4);
}

// Round 6
// 285.703 us; speedup vs baseline: 1.1194x; 1.1194x over previous
//
#include <hip/hip_runtime.h>

constexpr int IN_F  = 128;
constexpr int OUT_F = 64;

// ---------------- GEMM: h = feats @ weight ----------------
// Each wave computes 8 nodes x 64 cols; lane = output col.
// One LDS weight read feeds 8 FMAs (vs 1 in R1 -> 8x fewer ds_read).
__global__ void gemm_kernel(const float* __restrict__ feats,
                            const float* __restrict__ weight,
                            float* __restrict__ h, int n_nodes) {
    __shared__ float w[IN_F][OUT_F];  // 32 KB
    for (int i = threadIdx.x; i < IN_F * OUT_F; i += blockDim.x)
        w[i >> 6][i & 63] = weight[i];
    __syncthreads();

    const int lane   = threadIdx.x & 63;
    const int gwave  = (blockIdx.x * blockDim.x + threadIdx.x) >> 6;
    const int nwaves = (gridDim.x * blockDim.x) >> 6;

    for (int base = gwave * 8; base < n_nodes; base += nwaves * 8) {
        float acc[8] = {0.f, 0.f, 0.f, 0.f, 0.f, 0.f, 0.f, 0.f};
        const int nn = min(8, n_nodes - base);
        const float4* fr[8];
        #pragma unroll
        for (int t = 0; t < 8; ++t)
            fr[t] = reinterpret_cast<const float4*>(feats + (size_t)(base + (t < nn ? t : 0)) * IN_F);

        #pragma unroll 4
        for (int k4 = 0; k4 < IN_F / 4; ++k4) {
            float4 f[8];
            #pragma unroll
            for (int t = 0; t < 8; ++t) f[t] = fr[t][k4];  // wave-uniform broadcast loads
            #pragma unroll
            for (int c = 0; c < 4; ++c) {
                const float wv = w[k4 * 4 + c][lane];
                acc[0] += (&f[0].x)[c] * wv;
                acc[1] += (&f[1].x)[c] * wv;
                acc[2] += (&f[2].x)[c] * wv;
                acc[3] += (&f[3].x)[c] * wv;
                acc[4] += (&f[4].x)[c] * wv;
                acc[5] += (&f[5].x)[c] * wv;
                acc[6] += (&f[6].x)[c] * wv;
                acc[7] += (&f[7].x)[c] * wv;
            }
        }
        #pragma unroll
        for (int t = 0; t < 8; ++t)
            if (t < nn) h[(size_t)(base + t) * OUT_F + lane] = acc[t];
    }
}

// ---------------- CSR build ----------------
__global__ void hist_kernel(const int* __restrict__ dst, int* __restrict__ deg, int E) {
    const int stride = gridDim.x * blockDim.x;
    for (int e = blockIdx.x * blockDim.x + threadIdx.x; e < E; e += stride)
        atomicAdd(&deg[dst[e]], 1);
}

// K1: per-256-chunk inclusive scan; chunk totals to blksum
__global__ void scan_local(const int* __restrict__ deg, int* __restrict__ incl,
                           int* __restrict__ blksum, int N) {
    __shared__ int s[256];
    const int i = blockIdx.x * 256 + threadIdx.x;
    int v = (i < N) ? deg[i] : 0;
    s[threadIdx.x] = v;
    __syncthreads();
    for (int off = 1; off < 256; off <<= 1) {
        int t = (threadIdx.x >= off) ? s[threadIdx.x - off] : 0;
        __syncthreads();
        s[threadIdx.x] += t;
        __syncthreads();
    }
    if (i < N) incl[i] = s[threadIdx.x];
    if (threadIdx.x == 255) blksum[blockIdx.x] = s[255];
}

// K2: scan of chunk totals (nblk <= 256) -> exclusive base per chunk
__global__ void scan_blocks(int* __restrict__ blksum, int nblk) {
    __shared__ int s[256];
    const int v = (threadIdx.x < nblk) ? blksum[threadIdx.x] : 0;
    s[threadIdx.x] = v;
    __syncthreads();
    for (int off = 1; off < 256; off <<= 1) {
        int t = (threadIdx.x >= off) ? s[threadIdx.x - off] : 0;
        __syncthreads();
        s[threadIdx.x] += t;
        __syncthreads();
    }
    if (threadIdx.x < nblk) blksum[threadIdx.x] = s[threadIdx.x] - v;  // exclusive
}

// K3: finalize exclusive offsets + init scatter cursor
__global__ void scan_final(const int* __restrict__ deg, const int* __restrict__ incl,
                           const int* __restrict__ blksum, int* __restrict__ offs,
                           int* __restrict__ cursor, int N, int E) {
    const int i = blockIdx.x * 256 + threadIdx.x;
    if (i < N) {
        const int excl = blksum[blockIdx.x] + incl[i] - deg[i];
        offs[i]   = excl;
        cursor[i] = excl;
    }
    if (i == 0) offs[N] = E;
}

__global__ void scatter_kernel(const int* __restrict__ src, const int* __restrict__ dst,
                               int* __restrict__ cursor, int* __restrict__ bucket, int E) {
    const int stride = gridDim.x * blockDim.x;
    for (int e = blockIdx.x * blockDim.x + threadIdx.x; e < E; e += stride) {
        const int pos = atomicAdd(&cursor[dst[e]], 1);
        bucket[pos] = src[e];
    }
}

// ---------------- Pull-mode gather + bias + ReLU ----------------
// One wave per node; lane j accumulates column j over the node's in-edges.
__global__ void gather_kernel(const float* __restrict__ h, const int* __restrict__ bucket,
                              const int* __restrict__ offs, const float* __restrict__ bias,
                              float* __restrict__ out, int N) {
    const int lane   = threadIdx.x & 63;
    const int gwave  = (blockIdx.x * blockDim.x + threadIdx.x) >> 6;
    const int nwaves = (gridDim.x * blockDim.x) >> 6;
    const float b = bias[lane];
    for (int n = gwave; n < N; n += nwaves) {
        const int beg = offs[n], end = offs[n + 1];
        float acc = 0.f;
        int i = beg;
        for (; i + 4 <= end; i += 4) {
            const int s0 = bucket[i], s1 = bucket[i + 1], s2 = bucket[i + 2], s3 = bucket[i + 3];
            const float v0 = h[(size_t)s0 * OUT_F + lane];
            const float v1 = h[(size_t)s1 * OUT_F + lane];
            const float v2 = h[(size_t)s2 * OUT_F + lane];
            const float v3 = h[(size_t)s3 * OUT_F + lane];
            acc += v0; acc += v1; acc += v2; acc += v3;
        }
        for (; i < end; ++i) acc += h[(size_t)bucket[i] * OUT_F + lane];
        out[(size_t)n * OUT_F + lane] = fmaxf(acc + b, 0.f);
    }
}

extern "C" void kernel_launch(void* const* d_in, const int* in_sizes, int n_in,
                              void* d_out, int out_size, void* d_ws, size_t ws_size,
                              hipStream_t stream) {
    const float* feats  = (const float*)d_in[0];
    const float* weight = (const float*)d_in[1];
    const float* bias   = (const float*)d_in[2];
    const int*   src    = (const int*)d_in[3];
    const int*   dst    = (const int*)d_in[4];
    float* out = (float*)d_out;

    const int N = in_sizes[0] / IN_F;
    const int E = in_sizes[3];

    // workspace layout (~16.6 MB)
    float* h      = (float*)d_ws;             // N*64 f32
    int*   deg    = (int*)(h + (size_t)N * OUT_F);
    int*   incl   = deg + N;                  // inclusive-scan temp
    int*   offs   = incl + N;                 // N+1
    int*   cursor = offs + N + 1;
    int*   bucket = cursor + N;               // E
    int*   blksum = bucket + E;               // nblk

    const int nblk = (N + 255) / 256;         // 196 for N=50000 (<=256 required by scan_blocks)

    hipMemsetAsync(deg, 0, (size_t)N * sizeof(int), stream);

    gemm_kernel<<<(N / 8 + 3) / 4, 256, 0, stream>>>(feats, weight, h, N);
    hist_kernel<<<1024, 256, 0, stream>>>(dst, deg, E);
    scan_local<<<nblk, 256, 0, stream>>>(deg, incl, blksum, N);
    scan_blocks<<<1, 256, 0, stream>>>(blksum, nblk);
    scan_final<<<nblk, 256, 0, stream>>>(deg, incl, blksum, offs, cursor, N, E);
    scatter_kernel<<<1024, 256, 0, stream>>>(src, dst, cursor, bucket, E);
    // 2048 blocks x 256 = 8192 waves = full residency
    gather_kernel<<<2048, 256, 0, stream>>>(h, bucket, offs, bias, out, N);
}

// Round 7
// 247.927 us; speedup vs baseline: 1.2900x; 1.1524x over previous
//
#include <hip/hip_runtime.h>

constexpr int IN_F  = 128;
constexpr int OUT_F = 64;

// ---------------- GEMM: h = feats @ weight ----------------
// Block = 256 threads, tile = 32 nodes. feats tile staged in LDS via
// coalesced float4 loads; compute reads are LDS broadcasts (conflict-free).
// Each wave computes 8 nodes x 64 cols; lane = output col.
__global__ void gemm_kernel(const float* __restrict__ feats,
                            const float* __restrict__ weight,
                            float* __restrict__ h, int n_nodes) {
    __shared__ float w[IN_F][OUT_F];   // 32 KB
    __shared__ float f[32][IN_F];      // 16 KB feats tile
    for (int i = threadIdx.x; i < IN_F * OUT_F; i += blockDim.x)
        w[i >> 6][i & 63] = weight[i];

    const int lane = threadIdx.x & 63;
    const int wid  = threadIdx.x >> 6;  // wave id 0..3

    const int tile = blockIdx.x * 32;
    const int nn = min(32, n_nodes - tile);

    // stage feats tile: nn rows x 128 floats, coalesced float4
    for (int i = threadIdx.x; i < nn * (IN_F / 4); i += blockDim.x) {
        const int r = i >> 5, c4 = i & 31;
        reinterpret_cast<float4*>(f[r])[c4] =
            reinterpret_cast<const float4*>(feats + (size_t)(tile + r) * IN_F)[c4];
    }
    __syncthreads();

    const int row0 = wid * 8;
    float acc[8] = {0.f, 0.f, 0.f, 0.f, 0.f, 0.f, 0.f, 0.f};

    #pragma unroll 8
    for (int k4 = 0; k4 < IN_F / 4; ++k4) {
        float4 fv[8];
        #pragma unroll
        for (int t = 0; t < 8; ++t)
            fv[t] = reinterpret_cast<const float4*>(f[row0 + t])[k4];  // LDS broadcast
        #pragma unroll
        for (int c = 0; c < 4; ++c) {
            const float wv = w[k4 * 4 + c][lane];
            acc[0] += (&fv[0].x)[c] * wv;
            acc[1] += (&fv[1].x)[c] * wv;
            acc[2] += (&fv[2].x)[c] * wv;
            acc[3] += (&fv[3].x)[c] * wv;
            acc[4] += (&fv[4].x)[c] * wv;
            acc[5] += (&fv[5].x)[c] * wv;
            acc[6] += (&fv[6].x)[c] * wv;
            acc[7] += (&fv[7].x)[c] * wv;
        }
    }

    #pragma unroll
    for (int t = 0; t < 8; ++t) {
        const int n = tile + row0 + t;
        if (n < n_nodes) h[(size_t)n * OUT_F + lane] = acc[t];
    }
}

// ---------------- CSR build ----------------
__global__ void hist_kernel(const int* __restrict__ dst, int* __restrict__ deg, int E) {
    const int stride = gridDim.x * blockDim.x;
    for (int e = blockIdx.x * blockDim.x + threadIdx.x; e < E; e += stride)
        atomicAdd(&deg[dst[e]], 1);
}

// K1: per-256-chunk inclusive scan; chunk totals to blksum
__global__ void scan_local(const int* __restrict__ deg, int* __restrict__ incl,
                           int* __restrict__ blksum, int N) {
    __shared__ int s[256];
    const int i = blockIdx.x * 256 + threadIdx.x;
    int v = (i < N) ? deg[i] : 0;
    s[threadIdx.x] = v;
    __syncthreads();
    for (int off = 1; off < 256; off <<= 1) {
        int t = (threadIdx.x >= off) ? s[threadIdx.x - off] : 0;
        __syncthreads();
        s[threadIdx.x] += t;
        __syncthreads();
    }
    if (i < N) incl[i] = s[threadIdx.x];
    if (threadIdx.x == 255) blksum[blockIdx.x] = s[255];
}

// K2: scan of chunk totals (nblk <= 256) -> exclusive base per chunk
__global__ void scan_blocks(int* __restrict__ blksum, int nblk) {
    __shared__ int s[256];
    const int v = (threadIdx.x < nblk) ? blksum[threadIdx.x] : 0;
    s[threadIdx.x] = v;
    __syncthreads();
    for (int off = 1; off < 256; off <<= 1) {
        int t = (threadIdx.x >= off) ? s[threadIdx.x - off] : 0;
        __syncthreads();
        s[threadIdx.x] += t;
        __syncthreads();
    }
    if (threadIdx.x < nblk) blksum[threadIdx.x] = s[threadIdx.x] - v;  // exclusive
}

// K3: finalize exclusive offsets + init scatter cursor
__global__ void scan_final(const int* __restrict__ deg, const int* __restrict__ incl,
                           const int* __restrict__ blksum, int* __restrict__ offs,
                           int* __restrict__ cursor, int N, int E) {
    const int i = blockIdx.x * 256 + threadIdx.x;
    if (i < N) {
        const int excl = blksum[blockIdx.x] + incl[i] - deg[i];
        offs[i]   = excl;
        cursor[i] = excl;
    }
    if (i == 0) offs[N] = E;
}

__global__ void scatter_kernel(const int* __restrict__ src, const int* __restrict__ dst,
                               int* __restrict__ cursor, int* __restrict__ bucket, int E) {
    const int stride = gridDim.x * blockDim.x;
    for (int e = blockIdx.x * blockDim.x + threadIdx.x; e < E; e += stride) {
        const int pos = atomicAdd(&cursor[dst[e]], 1);
        bucket[pos] = src[e];
    }
}

// ---------------- Pull-mode gather + bias + ReLU ----------------
// One wave per node; lane j accumulates column j over the node's in-edges.
__global__ void gather_kernel(const float* __restrict__ h, const int* __restrict__ bucket,
                              const int* __restrict__ offs, const float* __restrict__ bias,
                              float* __restrict__ out, int N) {
    const int lane   = threadIdx.x & 63;
    const int gwave  = (blockIdx.x * blockDim.x + threadIdx.x) >> 6;
    const int nwaves = (gridDim.x * blockDim.x) >> 6;
    const float b = bias[lane];
    for (int n = gwave; n < N; n += nwaves) {
        const int beg = offs[n], end = offs[n + 1];
        float acc = 0.f;
        int i = beg;
        for (; i + 4 <= end; i += 4) {
            const int s0 = bucket[i], s1 = bucket[i + 1], s2 = bucket[i + 2], s3 = bucket[i + 3];
            const float v0 = h[(size_t)s0 * OUT_F + lane];
            const float v1 = h[(size_t)s1 * OUT_F + lane];
            const float v2 = h[(size_t)s2 * OUT_F + lane];
            const float v3 = h[(size_t)s3 * OUT_F + lane];
            acc += v0; acc += v1; acc += v2; acc += v3;
        }
        for (; i < end; ++i) acc += h[(size_t)bucket[i] * OUT_F + lane];
        out[(size_t)n * OUT_F + lane] = fmaxf(acc + b, 0.f);
    }
}

extern "C" void kernel_launch(void* const* d_in, const int* in_sizes, int n_in,
                              void* d_out, int out_size, void* d_ws, size_t ws_size,
                              hipStream_t stream) {
    const float* feats  = (const float*)d_in[0];
    const float* weight = (const float*)d_in[1];
    const float* bias   = (const float*)d_in[2];
    const int*   src    = (const int*)d_in[3];
    const int*   dst    = (const int*)d_in[4];
    float* out = (float*)d_out;

    const int N = in_sizes[0] / IN_F;
    const int E = in_sizes[3];

    // workspace layout (~16.6 MB)
    float* h      = (float*)d_ws;             // N*64 f32
    int*   deg    = (int*)(h + (size_t)N * OUT_F);
    int*   incl   = deg + N;                  // inclusive-scan temp
    int*   offs   = incl + N;                 // N+1
    int*   cursor = offs + N + 1;
    int*   bucket = cursor + N;               // E
    int*   blksum = bucket + E;               // nblk

    const int nblk = (N + 255) / 256;         // 196 for N=50000 (<=256 required by scan_blocks)

    hipMemsetAsync(deg, 0, (size_t)N * sizeof(int), stream);

    gemm_kernel<<<(N + 31) / 32, 256, 0, stream>>>(feats, weight, h, N);
    hist_kernel<<<1024, 256, 0, stream>>>(dst, deg, E);
    scan_local<<<nblk, 256, 0, stream>>>(deg, incl, blksum, N);
    scan_blocks<<<1, 256, 0, stream>>>(blksum, nblk);
    scan_final<<<nblk, 256, 0, stream>>>(deg, incl, blksum, offs, cursor, N, E);
    scatter_kernel<<<1024, 256, 0, stream>>>(src, dst, cursor, bucket, E);
    // 2048 blocks x 256 = 8192 waves = full residency
    gather_kernel<<<2048, 256, 0, stream>>>(h, bucket, offs, bias, out, N);
}